// Round 2
// baseline (2020.492 us; speedup 1.0000x reference)
//
#include <hip/hip_runtime.h>
#include <hip/hip_bf16.h>
#include <cstdint>

typedef unsigned short u16;
typedef __bf16 bf16x8 __attribute__((ext_vector_type(8)));
typedef float f32x4 __attribute__((ext_vector_type(4)));

#define AS1 __attribute__((address_space(1)))
#define AS3 __attribute__((address_space(3)))

__device__ __forceinline__ float b2f(u16 u) {
    union { float f; uint32_t i; } c; c.i = ((uint32_t)u) << 16; return c.f;
}
__device__ __forceinline__ u16 f2b(float f) {
    union { float f; uint32_t i; } c; c.f = f;
    return (u16)((c.i + 0x7fffu + ((c.i >> 16) & 1u)) >> 16);
}

#define BM 128
#define BN 128
#define BK 32
#define GK 1024
#define GN 1024

// C[b] (MxN row-major) = scale*(A[b] @ B[b]^T) [+bias(row|col) fp32] [+res(bf16)]
// A: MxK row-major bf16, B: NxK row-major bf16 (both K-contiguous). M=N=K=1024.
template <typename OutT>
__global__ __launch_bounds__(256) void gemm_nt(
    const u16* __restrict__ A, long long sA,
    const u16* __restrict__ B, long long sB,
    OutT* __restrict__ C, long long sC,
    const float* __restrict__ bias, int biasMode,   // 0 none, 1 row, 2 col
    const u16* __restrict__ res, long long sR,
    float scale)
{
    __shared__ u16 As[BM * BK];   // [m][k], 64B rows, contiguous (global_load_lds constraint)
    __shared__ u16 Bs[BN * BK];   // [n][k]

    const int t = threadIdx.x;
    const int bx = blockIdx.x, by = blockIdx.y, bz = blockIdx.z;
    const u16* Ab = A + (size_t)bz * sA + (size_t)(by * BM) * GK;
    const u16* Bb = B + (size_t)bz * sB + (size_t)(bx * BN) * GK;

    const int wave = t >> 6, lane = t & 63;
    const int l16 = lane & 15, quad = lane >> 4;
    const int wm = (wave >> 1) << 6;
    const int wn = (wave & 1) << 6;

    f32x4 acc[4][4] = {};

    // staging: 128 rows x 64B = 512 x 16B chunks; 256 threads -> 2 chunks each.
    // wave-contiguous: lanes of wave w cover chunks 64w..64w+63 (base + lane*16). 
    const int c0 = t, c1 = t + 256;
    const int r0 = c0 >> 2, o0 = (c0 & 3) << 3;
    const int r1 = c1 >> 2, o1 = (c1 & 3) << 3;

    for (int k0 = 0; k0 < GK; k0 += BK) {
        __syncthreads();
        __builtin_amdgcn_global_load_lds((AS1 const void*)(Ab + (size_t)r0 * GK + k0 + o0),
                                         (AS3 void*)((char*)As + c0 * 16), 16, 0, 0);
        __builtin_amdgcn_global_load_lds((AS1 const void*)(Ab + (size_t)r1 * GK + k0 + o1),
                                         (AS3 void*)((char*)As + c1 * 16), 16, 0, 0);
        __builtin_amdgcn_global_load_lds((AS1 const void*)(Bb + (size_t)r0 * GK + k0 + o0),
                                         (AS3 void*)((char*)Bs + c0 * 16), 16, 0, 0);
        __builtin_amdgcn_global_load_lds((AS1 const void*)(Bb + (size_t)r1 * GK + k0 + o1),
                                         (AS3 void*)((char*)Bs + c1 * 16), 16, 0, 0);
        __syncthreads();   // drains vmcnt(0): tiles resident

        bf16x8 af[4], bf[4];
        #pragma unroll
        for (int i = 0; i < 4; ++i) {
            af[i] = *(const bf16x8*)(As + (wm + i * 16 + l16) * BK + quad * 8);
            bf[i] = *(const bf16x8*)(Bs + (wn + i * 16 + l16) * BK + quad * 8);
        }
        #pragma unroll
        for (int mi = 0; mi < 4; ++mi)
            #pragma unroll
            for (int ni = 0; ni < 4; ++ni)
                acc[mi][ni] = __builtin_amdgcn_mfma_f32_16x16x32_bf16(af[mi], bf[ni], acc[mi][ni], 0, 0, 0);
    }

    OutT* Cb = C + (size_t)bz * sC;
    const u16* Rb = res ? res + (size_t)bz * sR : nullptr;
    const int row0 = by * BM + wm, col0 = bx * BN + wn;
    #pragma unroll
    for (int mi = 0; mi < 4; ++mi) {
        #pragma unroll
        for (int ni = 0; ni < 4; ++ni) {
            const int col = col0 + ni * 16 + l16;
            const float cb = (biasMode == 2) ? bias[col] : 0.0f;
            #pragma unroll
            for (int r = 0; r < 4; ++r) {
                const int row = row0 + mi * 16 + quad * 4 + r;   // C/D: col=lane&15, row=quad*4+reg
                float v = acc[mi][ni][r] * scale + cb;
                if (biasMode == 1) v += bias[row];
                if (Rb) v += b2f(Rb[(size_t)row * GN + col]);
                if constexpr (__is_same(OutT, float)) Cb[(size_t)row * GN + col] = v;
                else                                  Cb[(size_t)row * GN + col] = f2b(v);
            }
        }
    }
}

// in-place row softmax over 1024-wide bf16 rows, fp32 math
__global__ __launch_bounds__(256) void softmax_rows(u16* __restrict__ S)
{
    const size_t row = blockIdx.x;
    u16* p = S + row * 1024;
    const int t = threadIdx.x;
    ushort4 u = ((const ushort4*)p)[t];
    float v0 = b2f(u.x), v1 = b2f(u.y), v2 = b2f(u.z), v3 = b2f(u.w);

    float m = fmaxf(fmaxf(v0, v1), fmaxf(v2, v3));
    #pragma unroll
    for (int o = 32; o > 0; o >>= 1) m = fmaxf(m, __shfl_xor(m, o, 64));
    __shared__ float red[8];
    const int wave = t >> 6, lane = t & 63;
    if (lane == 0) red[wave] = m;
    __syncthreads();
    m = fmaxf(fmaxf(red[0], red[1]), fmaxf(red[2], red[3]));

    v0 = __expf(v0 - m); v1 = __expf(v1 - m); v2 = __expf(v2 - m); v3 = __expf(v3 - m);
    float s = v0 + v1 + v2 + v3;
    #pragma unroll
    for (int o = 32; o > 0; o >>= 1) s += __shfl_xor(s, o, 64);
    if (lane == 0) red[4 + wave] = s;
    __syncthreads();
    s = red[4] + red[5] + red[6] + red[7];
    const float inv = 1.0f / s;

    u.x = f2b(v0 * inv); u.y = f2b(v1 * inv); u.z = f2b(v2 * inv); u.w = f2b(v3 * inv);
    ((ushort4*)p)[t] = u;
}

// out[b](1024x1024 bf16) = transpose of in[b](1024x1024 bf16)
__global__ __launch_bounds__(256) void transpose_k(const u16* __restrict__ in, u16* __restrict__ out)
{
    __shared__ u16 tile[64][65];
    const size_t base = (size_t)blockIdx.z * 1024 * 1024;
    const u16* ib = in + base;
    u16* ob = out + base;
    const int t = threadIdx.x;
    const int vc = t & 15;
    const int rr0 = t >> 4;
    const int tr = blockIdx.y * 64, tc = blockIdx.x * 64;

    #pragma unroll
    for (int rr = 0; rr < 4; ++rr) {
        const int row = rr * 16 + rr0;
        ushort4 u = *(const ushort4*)(ib + (size_t)(tr + row) * 1024 + tc + vc * 4);
        tile[row][vc * 4 + 0] = u.x; tile[row][vc * 4 + 1] = u.y;
        tile[row][vc * 4 + 2] = u.z; tile[row][vc * 4 + 3] = u.w;
    }
    __syncthreads();
    #pragma unroll
    for (int rr = 0; rr < 4; ++rr) {
        const int orow = rr * 16 + rr0;
        ushort4 u;
        u.x = tile[vc * 4 + 0][orow]; u.y = tile[vc * 4 + 1][orow];
        u.z = tile[vc * 4 + 2][orow]; u.w = tile[vc * 4 + 3][orow];
        *(ushort4*)(ob + (size_t)(tc + orow) * 1024 + tr + vc * 4) = u;
    }
}

// out[b](1024x1024 bf16) = transpose of in[b](1024x1024 fp32), fused convert
__global__ __launch_bounds__(256) void tconv_k(const float* __restrict__ in, u16* __restrict__ out)
{
    __shared__ float tile[64][65];
    const size_t base = (size_t)blockIdx.z * 1024 * 1024;
    const float* ib = in + base;
    u16* ob = out + base;
    const int t = threadIdx.x;
    const int vc = t & 15;
    const int rr0 = t >> 4;
    const int tr = blockIdx.y * 64, tc = blockIdx.x * 64;

    #pragma unroll
    for (int rr = 0; rr < 4; ++rr) {
        const int row = rr * 16 + rr0;
        float4 u = *(const float4*)(ib + (size_t)(tr + row) * 1024 + tc + vc * 4);
        tile[row][vc * 4 + 0] = u.x; tile[row][vc * 4 + 1] = u.y;
        tile[row][vc * 4 + 2] = u.z; tile[row][vc * 4 + 3] = u.w;
    }
    __syncthreads();
    #pragma unroll
    for (int rr = 0; rr < 4; ++rr) {
        const int orow = rr * 16 + rr0;
        ushort4 u;
        u.x = f2b(tile[vc * 4 + 0][orow]); u.y = f2b(tile[vc * 4 + 1][orow]);
        u.z = f2b(tile[vc * 4 + 2][orow]); u.w = f2b(tile[vc * 4 + 3][orow]);
        *(ushort4*)(ob + (size_t)(tc + orow) * 1024 + tr + vc * 4) = u;
    }
}

// convert 8 fp32 1024x1024 weight matrices to bf16
struct WPack { const float* in[8]; u16* out[8]; };
__global__ __launch_bounds__(256) void convw_k(WPack p)
{
    const int m = blockIdx.y;
    const int i = (blockIdx.x * 256 + threadIdx.x) * 4;
    float4 v = *(const float4*)(p.in[m] + i);
    ushort4 s;
    s.x = f2b(v.x); s.y = f2b(v.y); s.z = f2b(v.z); s.w = f2b(v.w);
    *(ushort4*)(p.out[m] + i) = s;
}

extern "C" void kernel_launch(void* const* d_in, const int* in_sizes, int n_in,
                              void* d_out, int out_size, void* d_ws, size_t ws_size,
                              hipStream_t stream) {
    const size_t mat = (size_t)32 * 1024 * 1024;   // elems per batched (32,1024,1024) buffer
    const long long mm = 1024LL * 1024LL;          // per-batch stride
    const float sc = 1.0f / 32.0f;                 // 1/sqrt(1024)

    const float* x  = (const float*)d_in[0];
    const float* w1 = (const float*)d_in[1];  const float* b1 = (const float*)d_in[2];
    const float* w2 = (const float*)d_in[3];  const float* b2 = (const float*)d_in[4];
    const float* w3 = (const float*)d_in[5];  const float* b3 = (const float*)d_in[6];
    const float* w4 = (const float*)d_in[7];  const float* b4 = (const float*)d_in[8];
    const float* w5 = (const float*)d_in[9];  const float* b5 = (const float*)d_in[10];
    const float* w6 = (const float*)d_in[11]; const float* b6 = (const float*)d_in[12];
    const float* w7 = (const float*)d_in[13]; const float* b7 = (const float*)d_in[14];
    const float* wl = (const float*)d_in[15]; const float* bl = (const float*)d_in[16];
    float* out = (float*)d_out;

    // ws layout: 4 bf16 activation slots (64MB each) + 8 bf16 weight mats (2MB each) = 272MB
    u16* A = (u16*)d_ws;
    u16* Bv = A + mat;
    u16* Cv = A + 2 * mat;
    u16* Dv = A + 3 * mat;
    u16* wb = A + 4 * mat;
    u16 *w1b = wb, *w2b = wb + (1<<20), *w3b = wb + 2*(1<<20), *w4b = wb + 3*(1<<20),
        *w5b = wb + 4*(1<<20), *w6b = wb + 5*(1<<20), *w7b = wb + 6*(1<<20), *wlb = wb + 7*(1<<20);
    // d_out (128MB fp32) doubles as two 64MB bf16 scratch halves until the final GEMM
    u16* OutLo = (u16*)d_out;
    u16* OutHi = OutLo + mat;

    WPack wp;
    wp.in[0]=w1; wp.in[1]=w2; wp.in[2]=w3; wp.in[3]=w4; wp.in[4]=w5; wp.in[5]=w6; wp.in[6]=w7; wp.in[7]=wl;
    wp.out[0]=w1b; wp.out[1]=w2b; wp.out[2]=w3b; wp.out[3]=w4b; wp.out[4]=w5b; wp.out[5]=w6b; wp.out[6]=w7b; wp.out[7]=wlb;

    const dim3 blk(256);
    const dim3 gT(16, 16, 32), gG(8, 8, 32), gS(32 * 1024), gW(1024, 8);

    convw_k<<<gW, blk, 0, stream>>>(wp);
    tconv_k<<<gT, blk, 0, stream>>>(x, A);                                                      // A = x^T (b,n,c)
    gemm_nt<u16><<<gG, blk, 0, stream>>>(A, mm, w1b, 0, Bv, mm, b1, 2, nullptr, 0, 1.0f);       // B = Q1t
    gemm_nt<u16><<<gG, blk, 0, stream>>>(A, mm, w2b, 0, Cv, mm, b2, 2, nullptr, 0, 1.0f);       // C = K1t
    gemm_nt<u16><<<gG, blk, 0, stream>>>(w3b, 0, A, mm, Dv, mm, b3, 1, nullptr, 0, 1.0f);       // D = V1
    gemm_nt<u16><<<gG, blk, 0, stream>>>(Bv, mm, Cv, mm, OutLo, mm, nullptr, 0, nullptr, 0, sc);// S1
    softmax_rows<<<gS, blk, 0, stream>>>(OutLo);                                                // A1
    gemm_nt<u16><<<gG, blk, 0, stream>>>(OutLo, mm, Dv, mm, Bv, mm, nullptr, 0, A, mm, 1.0f);   // B = X1t = A1 V1^T + x^T
    transpose_k<<<gT, blk, 0, stream>>>(Bv, A);                                                 // A = X1 natural
    gemm_nt<u16><<<gG, blk, 0, stream>>>(w5b, 0, Bv, mm, Cv, mm, b5, 1, nullptr, 0, 1.0f);      // C = T5
    gemm_nt<u16><<<gG, blk, 0, stream>>>(wlb, 0, Cv, mm, Dv, mm, bl, 1, nullptr, 0, 1.0f);      // D = Q2t
    gemm_nt<u16><<<gG, blk, 0, stream>>>(w6b, 0, Bv, mm, Cv, mm, b6, 1, nullptr, 0, 1.0f);      // C = T6
    gemm_nt<u16><<<gG, blk, 0, stream>>>(wlb, 0, Cv, mm, OutLo, mm, bl, 1, nullptr, 0, 1.0f);   // OutLo = K2t
    gemm_nt<u16><<<gG, blk, 0, stream>>>(w7b, 0, Bv, mm, Cv, mm, b7, 1, nullptr, 0, 1.0f);      // C = T7
    gemm_nt<u16><<<gG, blk, 0, stream>>>(Cv, mm, wlb, 0, OutHi, mm, bl, 2, nullptr, 0, 1.0f);   // OutHi = V2
    gemm_nt<u16><<<gG, blk, 0, stream>>>(Dv, mm, OutLo, mm, Bv, mm, nullptr, 0, nullptr, 0, sc);// B = S2
    softmax_rows<<<gS, blk, 0, stream>>>(Bv);                                                   // A2
    gemm_nt<u16><<<gG, blk, 0, stream>>>(Bv, mm, OutHi, mm, Cv, mm, nullptr, 0, nullptr, 0, 1.0f); // C = O2t
    gemm_nt<float><<<gG, blk, 0, stream>>>(w4b, 0, Cv, mm, out, mm, b4, 1, A, mm, 1.0f);        // out = w4 O2 + b4 + X1
}

// Round 3
// 1937.712 us; speedup vs baseline: 1.0427x; 1.0427x over previous
//
#include <hip/hip_runtime.h>
#include <hip/hip_bf16.h>
#include <cstdint>

typedef unsigned short u16;
typedef __bf16 bf16x8 __attribute__((ext_vector_type(8)));
typedef float f32x4 __attribute__((ext_vector_type(4)));

#define AS1 __attribute__((address_space(1)))
#define AS3 __attribute__((address_space(3)))

__device__ __forceinline__ float b2f(u16 u) {
    union { float f; uint32_t i; } c; c.i = ((uint32_t)u) << 16; return c.f;
}
__device__ __forceinline__ u16 f2b(float f) {
    union { float f; uint32_t i; } c; c.f = f;
    return (u16)((c.i + 0x7fffu + ((c.i >> 16) & 1u)) >> 16);
}

#define BM 128
#define BN 128
#define BK 32
#define GK 1024
#define GN 1024

// C[b] (MxN row-major) = scale*(A[b] @ B[b]^T) [+bias(row|col) fp32] [+res(bf16)]
// A: MxK row-major bf16, B: NxK row-major bf16 (both K-contiguous). M=N=K=1024.
// Grid: 1-D, 2048 blocks. Decode puts all 64 tiles of a batch on ONE XCD
// (assumes consecutive block ids round-robin XCDs, id%8 heuristic) so the
// batch's 2MB+2MB operands live in that XCD's 4MB L2 instead of being
// re-fetched 8x from L3.
template <typename OutT>
__global__ __launch_bounds__(256) void gemm_nt(
    const u16* __restrict__ A, long long sA,
    const u16* __restrict__ B, long long sB,
    OutT* __restrict__ C, long long sC,
    const float* __restrict__ bias, int biasMode,   // 0 none, 1 row, 2 col
    const u16* __restrict__ res, long long sR,
    float scale)
{
    __shared__ u16 As[BM * BK];   // [m][k] 64B rows, 16B chunks XOR-swizzled
    __shared__ u16 Bs[BN * BK];   // [n][k]

    const int t = threadIdx.x;
    // XCD-locality decode: id = ((g*64 + tile) << 3) | xcd ; bz = g*8 + xcd
    const int id = blockIdx.x;
    const int xcd = id & 7;
    const int s = id >> 3;
    const int g = s >> 6;
    const int tile = s & 63;
    const int bz = g * 8 + xcd;
    const int bx = tile & 7;
    const int by = tile >> 3;

    const u16* Ab = A + (size_t)bz * sA + (size_t)(by * BM) * GK;
    const u16* Bb = B + (size_t)bz * sB + (size_t)(bx * BN) * GK;

    const int wave = t >> 6, lane = t & 63;
    const int l16 = lane & 15, quad = lane >> 4;
    const int wm = (wave >> 1) << 6;
    const int wn = (wave & 1) << 6;

    f32x4 acc[4][4] = {};

    // staging: 128 rows x 4 chunks of 16B = 512 chunks; 256 threads -> 2 each.
    // LDS chunk c holds global chunk (r = c>>2, j = (c&3) ^ ((r>>1)&3)):
    // XOR swizzle makes the quad-strided fragment ds_read_b128 hit all 8
    // bank groups uniformly (was 8-way group conflict, 8.4M cycles/dispatch).
    const int c0 = t, c1 = t + 256;
    const int r0 = c0 >> 2, o0 = (((c0 & 3) ^ ((r0 >> 1) & 3))) << 3;
    const int r1 = c1 >> 2, o1 = (((c1 & 3) ^ ((r1 >> 1) & 3))) << 3;

    for (int k0 = 0; k0 < GK; k0 += BK) {
        __syncthreads();
        __builtin_amdgcn_global_load_lds((AS1 const void*)(Ab + (size_t)r0 * GK + k0 + o0),
                                         (AS3 void*)((char*)As + c0 * 16), 16, 0, 0);
        __builtin_amdgcn_global_load_lds((AS1 const void*)(Ab + (size_t)r1 * GK + k0 + o1),
                                         (AS3 void*)((char*)As + c1 * 16), 16, 0, 0);
        __builtin_amdgcn_global_load_lds((AS1 const void*)(Bb + (size_t)r0 * GK + k0 + o0),
                                         (AS3 void*)((char*)Bs + c0 * 16), 16, 0, 0);
        __builtin_amdgcn_global_load_lds((AS1 const void*)(Bb + (size_t)r1 * GK + k0 + o1),
                                         (AS3 void*)((char*)Bs + c1 * 16), 16, 0, 0);
        __syncthreads();   // drains vmcnt(0): tiles resident

        bf16x8 af[4], bf[4];
        #pragma unroll
        for (int i = 0; i < 4; ++i) {
            const int ra = wm + i * 16 + l16;
            const int rb = wn + i * 16 + l16;
            af[i] = *(const bf16x8*)(As + ra * BK + ((quad ^ ((ra >> 1) & 3)) << 3));
            bf[i] = *(const bf16x8*)(Bs + rb * BK + ((quad ^ ((rb >> 1) & 3)) << 3));
        }
        #pragma unroll
        for (int mi = 0; mi < 4; ++mi)
            #pragma unroll
            for (int ni = 0; ni < 4; ++ni)
                acc[mi][ni] = __builtin_amdgcn_mfma_f32_16x16x32_bf16(af[mi], bf[ni], acc[mi][ni], 0, 0, 0);
    }

    OutT* Cb = C + (size_t)bz * sC;
    const u16* Rb = res ? res + (size_t)bz * sR : nullptr;
    const int row0 = by * BM + wm, col0 = bx * BN + wn;
    #pragma unroll
    for (int mi = 0; mi < 4; ++mi) {
        #pragma unroll
        for (int ni = 0; ni < 4; ++ni) {
            const int col = col0 + ni * 16 + l16;
            const float cb = (biasMode == 2) ? bias[col] : 0.0f;
            #pragma unroll
            for (int r = 0; r < 4; ++r) {
                const int row = row0 + mi * 16 + quad * 4 + r;   // C/D: col=lane&15, row=quad*4+reg
                float v = acc[mi][ni][r] * scale + cb;
                if (biasMode == 1) v += bias[row];
                if (Rb) v += b2f(Rb[(size_t)row * GN + col]);
                if constexpr (__is_same(OutT, float)) Cb[(size_t)row * GN + col] = v;
                else                                  Cb[(size_t)row * GN + col] = f2b(v);
            }
        }
    }
}

// in-place row softmax over 1024-wide bf16 rows, fp32 math
__global__ __launch_bounds__(256) void softmax_rows(u16* __restrict__ S)
{
    const size_t row = blockIdx.x;
    u16* p = S + row * 1024;
    const int t = threadIdx.x;
    ushort4 u = ((const ushort4*)p)[t];
    float v0 = b2f(u.x), v1 = b2f(u.y), v2 = b2f(u.z), v3 = b2f(u.w);

    float m = fmaxf(fmaxf(v0, v1), fmaxf(v2, v3));
    #pragma unroll
    for (int o = 32; o > 0; o >>= 1) m = fmaxf(m, __shfl_xor(m, o, 64));
    __shared__ float red[8];
    const int wave = t >> 6, lane = t & 63;
    if (lane == 0) red[wave] = m;
    __syncthreads();
    m = fmaxf(fmaxf(red[0], red[1]), fmaxf(red[2], red[3]));

    v0 = __expf(v0 - m); v1 = __expf(v1 - m); v2 = __expf(v2 - m); v3 = __expf(v3 - m);
    float s = v0 + v1 + v2 + v3;
    #pragma unroll
    for (int o = 32; o > 0; o >>= 1) s += __shfl_xor(s, o, 64);
    if (lane == 0) red[4 + wave] = s;
    __syncthreads();
    s = red[4] + red[5] + red[6] + red[7];
    const float inv = 1.0f / s;

    u.x = f2b(v0 * inv); u.y = f2b(v1 * inv); u.z = f2b(v2 * inv); u.w = f2b(v3 * inv);
    ((ushort4*)p)[t] = u;
}

// out[b](1024x1024 bf16) = transpose of in[b](1024x1024 bf16)
__global__ __launch_bounds__(256) void transpose_k(const u16* __restrict__ in, u16* __restrict__ out)
{
    __shared__ u16 tile[64][65];
    const size_t base = (size_t)blockIdx.z * 1024 * 1024;
    const u16* ib = in + base;
    u16* ob = out + base;
    const int t = threadIdx.x;
    const int vc = t & 15;
    const int rr0 = t >> 4;
    const int tr = blockIdx.y * 64, tc = blockIdx.x * 64;

    #pragma unroll
    for (int rr = 0; rr < 4; ++rr) {
        const int row = rr * 16 + rr0;
        ushort4 u = *(const ushort4*)(ib + (size_t)(tr + row) * 1024 + tc + vc * 4);
        tile[row][vc * 4 + 0] = u.x; tile[row][vc * 4 + 1] = u.y;
        tile[row][vc * 4 + 2] = u.z; tile[row][vc * 4 + 3] = u.w;
    }
    __syncthreads();
    #pragma unroll
    for (int rr = 0; rr < 4; ++rr) {
        const int orow = rr * 16 + rr0;
        ushort4 u;
        u.x = tile[vc * 4 + 0][orow]; u.y = tile[vc * 4 + 1][orow];
        u.z = tile[vc * 4 + 2][orow]; u.w = tile[vc * 4 + 3][orow];
        *(ushort4*)(ob + (size_t)(tc + orow) * 1024 + tr + vc * 4) = u;
    }
}

// out[b](1024x1024 bf16) = transpose of in[b](1024x1024 fp32), fused convert
__global__ __launch_bounds__(256) void tconv_k(const float* __restrict__ in, u16* __restrict__ out)
{
    __shared__ float tile[64][65];
    const size_t base = (size_t)blockIdx.z * 1024 * 1024;
    const float* ib = in + base;
    u16* ob = out + base;
    const int t = threadIdx.x;
    const int vc = t & 15;
    const int rr0 = t >> 4;
    const int tr = blockIdx.y * 64, tc = blockIdx.x * 64;

    #pragma unroll
    for (int rr = 0; rr < 4; ++rr) {
        const int row = rr * 16 + rr0;
        float4 u = *(const float4*)(ib + (size_t)(tr + row) * 1024 + tc + vc * 4);
        tile[row][vc * 4 + 0] = u.x; tile[row][vc * 4 + 1] = u.y;
        tile[row][vc * 4 + 2] = u.z; tile[row][vc * 4 + 3] = u.w;
    }
    __syncthreads();
    #pragma unroll
    for (int rr = 0; rr < 4; ++rr) {
        const int orow = rr * 16 + rr0;
        ushort4 u;
        u.x = f2b(tile[vc * 4 + 0][orow]); u.y = f2b(tile[vc * 4 + 1][orow]);
        u.z = f2b(tile[vc * 4 + 2][orow]); u.w = f2b(tile[vc * 4 + 3][orow]);
        *(ushort4*)(ob + (size_t)(tc + orow) * 1024 + tr + vc * 4) = u;
    }
}

// convert 8 fp32 1024x1024 weight matrices to bf16
struct WPack { const float* in[8]; u16* out[8]; };
__global__ __launch_bounds__(256) void convw_k(WPack p)
{
    const int m = blockIdx.y;
    const int i = (blockIdx.x * 256 + threadIdx.x) * 4;
    float4 v = *(const float4*)(p.in[m] + i);
    ushort4 s;
    s.x = f2b(v.x); s.y = f2b(v.y); s.z = f2b(v.z); s.w = f2b(v.w);
    *(ushort4*)(p.out[m] + i) = s;
}

extern "C" void kernel_launch(void* const* d_in, const int* in_sizes, int n_in,
                              void* d_out, int out_size, void* d_ws, size_t ws_size,
                              hipStream_t stream) {
    const size_t mat = (size_t)32 * 1024 * 1024;   // elems per batched (32,1024,1024) buffer
    const long long mm = 1024LL * 1024LL;          // per-batch stride
    const float sc = 1.0f / 32.0f;                 // 1/sqrt(1024)

    const float* x  = (const float*)d_in[0];
    const float* w1 = (const float*)d_in[1];  const float* b1 = (const float*)d_in[2];
    const float* w2 = (const float*)d_in[3];  const float* b2 = (const float*)d_in[4];
    const float* w3 = (const float*)d_in[5];  const float* b3 = (const float*)d_in[6];
    const float* w4 = (const float*)d_in[7];  const float* b4 = (const float*)d_in[8];
    const float* w5 = (const float*)d_in[9];  const float* b5 = (const float*)d_in[10];
    const float* w6 = (const float*)d_in[11]; const float* b6 = (const float*)d_in[12];
    const float* w7 = (const float*)d_in[13]; const float* b7 = (const float*)d_in[14];
    const float* wl = (const float*)d_in[15]; const float* bl = (const float*)d_in[16];
    float* out = (float*)d_out;

    // ws layout: 4 bf16 activation slots (64MB each) + 8 bf16 weight mats (2MB each)
    u16* A = (u16*)d_ws;
    u16* Bv = A + mat;
    u16* Cv = A + 2 * mat;
    u16* Dv = A + 3 * mat;
    u16* wb = A + 4 * mat;
    u16 *w1b = wb, *w2b = wb + (1<<20), *w3b = wb + 2*(1<<20), *w4b = wb + 3*(1<<20),
        *w5b = wb + 4*(1<<20), *w6b = wb + 5*(1<<20), *w7b = wb + 6*(1<<20), *wlb = wb + 7*(1<<20);
    // d_out (128MB fp32) doubles as two 64MB bf16 scratch halves until the final GEMM
    u16* OutLo = (u16*)d_out;
    u16* OutHi = OutLo + mat;

    WPack wp;
    wp.in[0]=w1; wp.in[1]=w2; wp.in[2]=w3; wp.in[3]=w4; wp.in[4]=w5; wp.in[5]=w6; wp.in[6]=w7; wp.in[7]=wl;
    wp.out[0]=w1b; wp.out[1]=w2b; wp.out[2]=w3b; wp.out[3]=w4b; wp.out[4]=w5b; wp.out[5]=w6b; wp.out[6]=w7b; wp.out[7]=wlb;

    const dim3 blk(256);
    const dim3 gT(16, 16, 32), gG(2048), gS(32 * 1024), gW(1024, 8);

    convw_k<<<gW, blk, 0, stream>>>(wp);
    tconv_k<<<gT, blk, 0, stream>>>(x, A);                                                      // A = x^T (b,n,c)
    gemm_nt<u16><<<gG, blk, 0, stream>>>(A, mm, w1b, 0, Bv, mm, b1, 2, nullptr, 0, 1.0f);       // B = Q1t
    gemm_nt<u16><<<gG, blk, 0, stream>>>(A, mm, w2b, 0, Cv, mm, b2, 2, nullptr, 0, 1.0f);       // C = K1t
    gemm_nt<u16><<<gG, blk, 0, stream>>>(w3b, 0, A, mm, Dv, mm, b3, 1, nullptr, 0, 1.0f);       // D = V1
    gemm_nt<u16><<<gG, blk, 0, stream>>>(Bv, mm, Cv, mm, OutLo, mm, nullptr, 0, nullptr, 0, sc);// S1
    softmax_rows<<<gS, blk, 0, stream>>>(OutLo);                                                // A1
    gemm_nt<u16><<<gG, blk, 0, stream>>>(OutLo, mm, Dv, mm, Bv, mm, nullptr, 0, A, mm, 1.0f);   // B = X1t = A1 V1^T + x^T
    transpose_k<<<gT, blk, 0, stream>>>(Bv, A);                                                 // A = X1 natural
    gemm_nt<u16><<<gG, blk, 0, stream>>>(w5b, 0, Bv, mm, Cv, mm, b5, 1, nullptr, 0, 1.0f);      // C = T5
    gemm_nt<u16><<<gG, blk, 0, stream>>>(wlb, 0, Cv, mm, Dv, mm, bl, 1, nullptr, 0, 1.0f);      // D = Q2t
    gemm_nt<u16><<<gG, blk, 0, stream>>>(w6b, 0, Bv, mm, Cv, mm, b6, 1, nullptr, 0, 1.0f);      // C = T6
    gemm_nt<u16><<<gG, blk, 0, stream>>>(wlb, 0, Cv, mm, OutLo, mm, bl, 1, nullptr, 0, 1.0f);   // OutLo = K2t
    gemm_nt<u16><<<gG, blk, 0, stream>>>(w7b, 0, Bv, mm, Cv, mm, b7, 1, nullptr, 0, 1.0f);      // C = T7
    gemm_nt<u16><<<gG, blk, 0, stream>>>(Cv, mm, wlb, 0, OutHi, mm, bl, 2, nullptr, 0, 1.0f);   // OutHi = V2
    gemm_nt<u16><<<gG, blk, 0, stream>>>(Dv, mm, OutLo, mm, Bv, mm, nullptr, 0, nullptr, 0, sc);// B = S2
    softmax_rows<<<gS, blk, 0, stream>>>(Bv);                                                   // A2
    gemm_nt<u16><<<gG, blk, 0, stream>>>(Bv, mm, OutHi, mm, Cv, mm, nullptr, 0, nullptr, 0, 1.0f); // C = O2t
    gemm_nt<float><<<gG, blk, 0, stream>>>(w4b, 0, Cv, mm, out, mm, b4, 1, A, mm, 1.0f);        // out = w4 O2 + b4 + X1
}

// Round 4
// 1774.989 us; speedup vs baseline: 1.1383x; 1.0917x over previous
//
#include <hip/hip_runtime.h>
#include <hip/hip_bf16.h>
#include <cstdint>

typedef unsigned short u16;
typedef __bf16 bf16x8 __attribute__((ext_vector_type(8)));
typedef float f32x4 __attribute__((ext_vector_type(4)));
typedef unsigned short us8 __attribute__((ext_vector_type(8)));

#define AS1 __attribute__((address_space(1)))
#define AS3 __attribute__((address_space(3)))

__device__ __forceinline__ float b2f(u16 u) {
    union { float f; uint32_t i; } c; c.i = ((uint32_t)u) << 16; return c.f;
}
__device__ __forceinline__ u16 f2b(float f) {
    union { float f; uint32_t i; } c; c.f = f;
    return (u16)((c.i + 0x7fffu + ((c.i >> 16) & 1u)) >> 16);
}

#define BM 128
#define BN 128
#define BK 64
#define GK 1024
#define GN 1024
#define NKT (GK / BK)   // 16 k-iterations

// C[b] (MxN row-major) = scale*(A[b] @ B[b]^T) [+bias(row|col) fp32] [+res(bf16)]
// A: MxK row-major bf16, B: NxK row-major bf16. M=N=K=1024.
// Double-buffered LDS (BK=64), prefetch k+1 issued before computing k so the
// vmcnt(0) drain at each barrier covers loads that aged a full compute phase.
// LDS 16B chunks XOR-swizzled: slot (r, js) holds global chunk js^(r&7).
template <typename OutT>
__global__ __launch_bounds__(256) void gemm_nt(
    const u16* __restrict__ A, long long sA,
    const u16* __restrict__ B, long long sB,
    OutT* __restrict__ C, long long sC,
    const float* __restrict__ bias, int biasMode,   // 0 none, 1 row, 2 col
    const u16* __restrict__ res, long long sR,
    float scale)
{
    // buf p: A at p*32768, B at p*32768+16384 (16 KB each). Epilogue reuses all
    // 64 KB as a 128x128 f32 C-tile (8-f32 chunks XOR-swizzled by row for banks).
    __shared__ __align__(16) char smem[65536];

    const int t = threadIdx.x;
    const int bx = blockIdx.x, by = blockIdx.y, bz = blockIdx.z;

    const u16* Ab = A + (size_t)bz * sA + (size_t)(by * BM) * GK;
    const u16* Bb = B + (size_t)bz * sB + (size_t)(bx * BN) * GK;

    const int wave = t >> 6, lane = t & 63;
    const int l16 = lane & 15, quad = lane >> 4;
    const int wm = (wave >> 1) << 6;
    const int wn = (wave & 1) << 6;

    f32x4 acc[4][4] = {};

    // staging: per operand-buffer 1024 chunks of 16B; thread t owns chunks t+256i.
    // slot c: r=c>>3, js=c&7 -> global chunk jg = js ^ (r&7).
    int goff[4], loff[4];
    #pragma unroll
    for (int i = 0; i < 4; ++i) {
        const int c = t + 256 * i;
        const int r = c >> 3, js = c & 7;
        const int jg = js ^ (r & 7);
        goff[i] = r * GK + jg * 8;   // element offset (k0 added per iter)
        loff[i] = c * 16;            // byte offset in buffer
    }

    #define STAGE(k0, p)                                                              \
        _Pragma("unroll")                                                             \
        for (int i = 0; i < 4; ++i) {                                                 \
            __builtin_amdgcn_global_load_lds((AS1 const void*)(Ab + goff[i] + (k0)),  \
                (AS3 void*)(smem + (p) * 32768 + loff[i]), 16, 0, 0);                 \
            __builtin_amdgcn_global_load_lds((AS1 const void*)(Bb + goff[i] + (k0)),  \
                (AS3 void*)(smem + (p) * 32768 + 16384 + loff[i]), 16, 0, 0);         \
        }

    STAGE(0, 0)
    for (int kt = 0; kt < NKT; ++kt) {
        __syncthreads();                       // drains tile kt's loads (aged by prior compute)
        if (kt + 1 < NKT) { STAGE((kt + 1) * BK, (kt + 1) & 1) }

        const u16* Ap = (const u16*)(smem + (kt & 1) * 32768);
        const u16* Bp = Ap + 16384 / 2;
        #pragma unroll
        for (int kk = 0; kk < 2; ++kk) {
            const int jx = (kk * 4 + quad) ^ (l16 & 7);   // rows: (base+l16)&7 == l16&7
            bf16x8 af[4], bf[4];
            #pragma unroll
            for (int i = 0; i < 4; ++i) {
                af[i] = *(const bf16x8*)(Ap + (wm + i * 16 + l16) * BK + jx * 8);
                bf[i] = *(const bf16x8*)(Bp + (wn + i * 16 + l16) * BK + jx * 8);
            }
            #pragma unroll
            for (int mi = 0; mi < 4; ++mi)
                #pragma unroll
                for (int ni = 0; ni < 4; ++ni)
                    acc[mi][ni] = __builtin_amdgcn_mfma_f32_16x16x32_bf16(af[mi], bf[ni], acc[mi][ni], 0, 0, 0);
        }
    }

    // ---- epilogue: acc -> LDS (f32, swizzled) -> coalesced vector stores ----
    __syncthreads();   // last ds_reads done; safe to overwrite smem
    float* Cs = (float*)smem;
    #pragma unroll
    for (int mi = 0; mi < 4; ++mi) {
        #pragma unroll
        for (int ni = 0; ni < 4; ++ni) {
            const int col = wn + ni * 16 + l16;
            const int cc = col >> 3, cw = col & 7;
            #pragma unroll
            for (int r = 0; r < 4; ++r) {
                const int row = wm + mi * 16 + quad * 4 + r;   // C/D: col=lane&15, row=quad*4+reg
                Cs[row * 128 + (((cc ^ (row & 15)) << 3) | cw)] = acc[mi][ni][r];
            }
        }
    }
    __syncthreads();

    if constexpr (__is_same(OutT, u16)) {
        // 8 steps x 16B/lane, lane-consecutive chunks -> fully coalesced
        #pragma unroll
        for (int i = 0; i < 8; ++i) {
            const int ch = t + 256 * i;
            const int lr = ch >> 4, cc = ch & 15;
            const float* src = Cs + lr * 128 + ((cc ^ (lr & 15)) << 3);
            float4 a = *(const float4*)(src);
            float4 b = *(const float4*)(src + 4);
            const int grow = by * BM + lr;
            const int gcol = bx * BN + cc * 8;
            const float br = (biasMode == 1) ? bias[grow] : 0.0f;
            float v[8] = {a.x, a.y, a.z, a.w, b.x, b.y, b.z, b.w};
            #pragma unroll
            for (int j = 0; j < 8; ++j) v[j] = v[j] * scale + br;
            if (biasMode == 2) {
                float4 c1 = *(const float4*)(bias + gcol);
                float4 c2 = *(const float4*)(bias + gcol + 4);
                v[0] += c1.x; v[1] += c1.y; v[2] += c1.z; v[3] += c1.w;
                v[4] += c2.x; v[5] += c2.y; v[6] += c2.z; v[7] += c2.w;
            }
            if (res) {
                us8 rv = *(const us8*)(res + (size_t)bz * sR + (size_t)grow * GN + gcol);
                #pragma unroll
                for (int j = 0; j < 8; ++j) v[j] += b2f(rv[j]);
            }
            us8 o;
            #pragma unroll
            for (int j = 0; j < 8; ++j) o[j] = f2b(v[j]);
            *(us8*)((u16*)C + (size_t)bz * sC + (size_t)grow * GN + gcol) = o;
        }
    } else {
        // fp32 out: 16 steps x 16B/lane
        #pragma unroll
        for (int i = 0; i < 16; ++i) {
            const int ch = t + 256 * i;
            const int lr = ch >> 5, cc4 = ch & 31;
            const float* src = Cs + lr * 128 + (((cc4 >> 1) ^ (lr & 15)) << 3) + (cc4 & 1) * 4;
            float4 a = *(const float4*)(src);
            const int grow = by * BM + lr;
            const int gcol = bx * BN + cc4 * 4;
            const float br = (biasMode == 1) ? bias[grow] : 0.0f;
            float v[4] = {a.x, a.y, a.z, a.w};
            #pragma unroll
            for (int j = 0; j < 4; ++j) v[j] = v[j] * scale + br;
            if (biasMode == 2) {
                float4 c1 = *(const float4*)(bias + gcol);
                v[0] += c1.x; v[1] += c1.y; v[2] += c1.z; v[3] += c1.w;
            }
            if (res) {
                ushort4 rv = *(const ushort4*)(res + (size_t)bz * sR + (size_t)grow * GN + gcol);
                v[0] += b2f(rv.x); v[1] += b2f(rv.y); v[2] += b2f(rv.z); v[3] += b2f(rv.w);
            }
            float4 o = {v[0], v[1], v[2], v[3]};
            *(float4*)((float*)C + (size_t)bz * sC + (size_t)grow * GN + gcol) = o;
        }
    }
    #undef STAGE
}

// in-place row softmax over 1024-wide bf16 rows, fp32 math
__global__ __launch_bounds__(256) void softmax_rows(u16* __restrict__ S)
{
    const size_t row = blockIdx.x;
    u16* p = S + row * 1024;
    const int t = threadIdx.x;
    ushort4 u = ((const ushort4*)p)[t];
    float v0 = b2f(u.x), v1 = b2f(u.y), v2 = b2f(u.z), v3 = b2f(u.w);

    float m = fmaxf(fmaxf(v0, v1), fmaxf(v2, v3));
    #pragma unroll
    for (int o = 32; o > 0; o >>= 1) m = fmaxf(m, __shfl_xor(m, o, 64));
    __shared__ float red[8];
    const int wave = t >> 6, lane = t & 63;
    if (lane == 0) red[wave] = m;
    __syncthreads();
    m = fmaxf(fmaxf(red[0], red[1]), fmaxf(red[2], red[3]));

    v0 = __expf(v0 - m); v1 = __expf(v1 - m); v2 = __expf(v2 - m); v3 = __expf(v3 - m);
    float s = v0 + v1 + v2 + v3;
    #pragma unroll
    for (int o = 32; o > 0; o >>= 1) s += __shfl_xor(s, o, 64);
    if (lane == 0) red[4 + wave] = s;
    __syncthreads();
    s = red[4] + red[5] + red[6] + red[7];
    const float inv = 1.0f / s;

    u.x = f2b(v0 * inv); u.y = f2b(v1 * inv); u.z = f2b(v2 * inv); u.w = f2b(v3 * inv);
    ((ushort4*)p)[t] = u;
}

// out[b](1024x1024 bf16) = transpose of in[b](1024x1024 bf16)
__global__ __launch_bounds__(256) void transpose_k(const u16* __restrict__ in, u16* __restrict__ out)
{
    __shared__ u16 tile[64][65];
    const size_t base = (size_t)blockIdx.z * 1024 * 1024;
    const u16* ib = in + base;
    u16* ob = out + base;
    const int t = threadIdx.x;
    const int vc = t & 15;
    const int rr0 = t >> 4;
    const int tr = blockIdx.y * 64, tc = blockIdx.x * 64;

    #pragma unroll
    for (int rr = 0; rr < 4; ++rr) {
        const int row = rr * 16 + rr0;
        ushort4 u = *(const ushort4*)(ib + (size_t)(tr + row) * 1024 + tc + vc * 4);
        tile[row][vc * 4 + 0] = u.x; tile[row][vc * 4 + 1] = u.y;
        tile[row][vc * 4 + 2] = u.z; tile[row][vc * 4 + 3] = u.w;
    }
    __syncthreads();
    #pragma unroll
    for (int rr = 0; rr < 4; ++rr) {
        const int orow = rr * 16 + rr0;
        ushort4 u;
        u.x = tile[vc * 4 + 0][orow]; u.y = tile[vc * 4 + 1][orow];
        u.z = tile[vc * 4 + 2][orow]; u.w = tile[vc * 4 + 3][orow];
        *(ushort4*)(ob + (size_t)(tc + orow) * 1024 + tr + vc * 4) = u;
    }
}

// out[b](1024x1024 bf16) = transpose of in[b](1024x1024 fp32), fused convert
__global__ __launch_bounds__(256) void tconv_k(const float* __restrict__ in, u16* __restrict__ out)
{
    __shared__ float tile[64][65];
    const size_t base = (size_t)blockIdx.z * 1024 * 1024;
    const float* ib = in + base;
    u16* ob = out + base;
    const int t = threadIdx.x;
    const int vc = t & 15;
    const int rr0 = t >> 4;
    const int tr = blockIdx.y * 64, tc = blockIdx.x * 64;

    #pragma unroll
    for (int rr = 0; rr < 4; ++rr) {
        const int row = rr * 16 + rr0;
        float4 u = *(const float4*)(ib + (size_t)(tr + row) * 1024 + tc + vc * 4);
        tile[row][vc * 4 + 0] = u.x; tile[row][vc * 4 + 1] = u.y;
        tile[row][vc * 4 + 2] = u.z; tile[row][vc * 4 + 3] = u.w;
    }
    __syncthreads();
    #pragma unroll
    for (int rr = 0; rr < 4; ++rr) {
        const int orow = rr * 16 + rr0;
        ushort4 u;
        u.x = f2b(tile[vc * 4 + 0][orow]); u.y = f2b(tile[vc * 4 + 1][orow]);
        u.z = f2b(tile[vc * 4 + 2][orow]); u.w = f2b(tile[vc * 4 + 3][orow]);
        *(ushort4*)(ob + (size_t)(tc + orow) * 1024 + tr + vc * 4) = u;
    }
}

// convert 8 fp32 1024x1024 weight matrices to bf16
struct WPack { const float* in[8]; u16* out[8]; };
__global__ __launch_bounds__(256) void convw_k(WPack p)
{
    const int m = blockIdx.y;
    const int i = (blockIdx.x * 256 + threadIdx.x) * 4;
    float4 v = *(const float4*)(p.in[m] + i);
    ushort4 s;
    s.x = f2b(v.x); s.y = f2b(v.y); s.z = f2b(v.z); s.w = f2b(v.w);
    *(ushort4*)(p.out[m] + i) = s;
}

extern "C" void kernel_launch(void* const* d_in, const int* in_sizes, int n_in,
                              void* d_out, int out_size, void* d_ws, size_t ws_size,
                              hipStream_t stream) {
    const size_t mat = (size_t)32 * 1024 * 1024;   // elems per batched (32,1024,1024) buffer
    const long long mm = 1024LL * 1024LL;          // per-batch stride
    const float sc = 1.0f / 32.0f;                 // 1/sqrt(1024)

    const float* x  = (const float*)d_in[0];
    const float* w1 = (const float*)d_in[1];  const float* b1 = (const float*)d_in[2];
    const float* w2 = (const float*)d_in[3];  const float* b2 = (const float*)d_in[4];
    const float* w3 = (const float*)d_in[5];  const float* b3 = (const float*)d_in[6];
    const float* w4 = (const float*)d_in[7];  const float* b4 = (const float*)d_in[8];
    const float* w5 = (const float*)d_in[9];  const float* b5 = (const float*)d_in[10];
    const float* w6 = (const float*)d_in[11]; const float* b6 = (const float*)d_in[12];
    const float* w7 = (const float*)d_in[13]; const float* b7 = (const float*)d_in[14];
    const float* wl = (const float*)d_in[15]; const float* bl = (const float*)d_in[16];
    float* out = (float*)d_out;

    u16* A = (u16*)d_ws;
    u16* Bv = A + mat;
    u16* Cv = A + 2 * mat;
    u16* Dv = A + 3 * mat;
    u16* wb = A + 4 * mat;
    u16 *w1b = wb, *w2b = wb + (1<<20), *w3b = wb + 2*(1<<20), *w4b = wb + 3*(1<<20),
        *w5b = wb + 4*(1<<20), *w6b = wb + 5*(1<<20), *w7b = wb + 6*(1<<20), *wlb = wb + 7*(1<<20);
    u16* OutLo = (u16*)d_out;
    u16* OutHi = OutLo + mat;

    WPack wp;
    wp.in[0]=w1; wp.in[1]=w2; wp.in[2]=w3; wp.in[3]=w4; wp.in[4]=w5; wp.in[5]=w6; wp.in[6]=w7; wp.in[7]=wl;
    wp.out[0]=w1b; wp.out[1]=w2b; wp.out[2]=w3b; wp.out[3]=w4b; wp.out[4]=w5b; wp.out[5]=w6b; wp.out[6]=w7b; wp.out[7]=wlb;

    const dim3 blk(256);
    const dim3 gT(16, 16, 32), gG(8, 8, 32), gS(32 * 1024), gW(1024, 8);

    convw_k<<<gW, blk, 0, stream>>>(wp);
    tconv_k<<<gT, blk, 0, stream>>>(x, A);                                                      // A = x^T (b,n,c)
    gemm_nt<u16><<<gG, blk, 0, stream>>>(A, mm, w1b, 0, Bv, mm, b1, 2, nullptr, 0, 1.0f);       // B = Q1t
    gemm_nt<u16><<<gG, blk, 0, stream>>>(A, mm, w2b, 0, Cv, mm, b2, 2, nullptr, 0, 1.0f);       // C = K1t
    gemm_nt<u16><<<gG, blk, 0, stream>>>(w3b, 0, A, mm, Dv, mm, b3, 1, nullptr, 0, 1.0f);       // D = V1
    gemm_nt<u16><<<gG, blk, 0, stream>>>(Bv, mm, Cv, mm, OutLo, mm, nullptr, 0, nullptr, 0, sc);// S1
    softmax_rows<<<gS, blk, 0, stream>>>(OutLo);                                                // A1
    gemm_nt<u16><<<gG, blk, 0, stream>>>(OutLo, mm, Dv, mm, Bv, mm, nullptr, 0, A, mm, 1.0f);   // B = X1t = A1 V1^T + x^T
    transpose_k<<<gT, blk, 0, stream>>>(Bv, A);                                                 // A = X1 natural
    gemm_nt<u16><<<gG, blk, 0, stream>>>(w5b, 0, Bv, mm, Cv, mm, b5, 1, nullptr, 0, 1.0f);      // C = T5
    gemm_nt<u16><<<gG, blk, 0, stream>>>(wlb, 0, Cv, mm, Dv, mm, bl, 1, nullptr, 0, 1.0f);      // D = Q2t
    gemm_nt<u16><<<gG, blk, 0, stream>>>(w6b, 0, Bv, mm, Cv, mm, b6, 1, nullptr, 0, 1.0f);      // C = T6
    gemm_nt<u16><<<gG, blk, 0, stream>>>(wlb, 0, Cv, mm, OutLo, mm, bl, 1, nullptr, 0, 1.0f);   // OutLo = K2t
    gemm_nt<u16><<<gG, blk, 0, stream>>>(w7b, 0, Bv, mm, Cv, mm, b7, 1, nullptr, 0, 1.0f);      // C = T7
    gemm_nt<u16><<<gG, blk, 0, stream>>>(Cv, mm, wlb, 0, OutHi, mm, bl, 2, nullptr, 0, 1.0f);   // OutHi = V2
    gemm_nt<u16><<<gG, blk, 0, stream>>>(Dv, mm, OutLo, mm, Bv, mm, nullptr, 0, nullptr, 0, sc);// B = S2
    softmax_rows<<<gS, blk, 0, stream>>>(Bv);                                                   // A2
    gemm_nt<u16><<<gG, blk, 0, stream>>>(Bv, mm, OutHi, mm, Cv, mm, nullptr, 0, nullptr, 0, 1.0f); // C = O2t
    gemm_nt<float><<<gG, blk, 0, stream>>>(w4b, 0, Cv, mm, out, mm, b4, 1, A, mm, 1.0f);        // out = w4 O2 + b4 + X1
}